// Round 3
// baseline (707.752 us; speedup 1.0000x reference)
//
#include <hip/hip_runtime.h>

#define B_  512
#define L_  100
#define LP_ 112      // L padded to 7*16
#define D_  128
#define SH_ 136      // ushort stride of H/U4/P rows (16B-aligned, odd*8 -> bank spread)
#define SA_ 113      // float stride of alpha tile

typedef unsigned short ushort_t;
typedef __attribute__((ext_vector_type(8))) unsigned short us8;
typedef __attribute__((ext_vector_type(8))) __bf16 bf8;
typedef __attribute__((ext_vector_type(4))) float f4;
typedef __attribute__((ext_vector_type(4))) float f4v;

__device__ __forceinline__ float b2f(ushort_t u) {
  union { unsigned i; float f; } v; v.i = ((unsigned)u) << 16; return v.f;
}
__device__ __forceinline__ ushort_t f2b(float f) {
  unsigned u = __float_as_uint(f);
  u += 0x7fffu + ((u >> 16) & 1u);   // RNE
  return (ushort_t)(u >> 16);
}

__global__ __launch_bounds__(256, 1)
void CombineGraph_kernel(const int* __restrict__ inp, const int* __restrict__ adjG,
                         const float* __restrict__ embF,
                         const float* __restrict__ a0F, const float* __restrict__ a1F,
                         const float* __restrict__ a2F, const float* __restrict__ a3F,
                         float* __restrict__ outG) {
  __shared__ __align__(16) ushort_t Hs[LP_ * SH_];       // h rows (bf16 bits)
  __shared__ __align__(16) ushort_t U4s[4 * 16 * SH_];   // U_k tiles for current 16 rows
  __shared__ __align__(16) ushort_t Ps[LP_ * SH_];       // softmaxed alpha (bf16), cols>=112 zero
  __shared__ float    alphaS[16 * SA_];                  // masked logits, f32
  __shared__ unsigned char adjS[16 * 128];               // adj tile
  __shared__ float    aVf[4 * 128];                      // a_k in f32
  // total ~89.7 KB -> 1 block/CU

  const int b = blockIdx.x;
  const int tid = threadIdx.x;
  const int w = tid >> 6, lane = tid & 63;
  const int c = lane & 15, q = lane >> 4;

  // a_k -> f32 LDS (inputs are f32)
  for (int u = tid; u < 512; u += 256) {
    int k = u >> 7, d = u & 127;
    const float* ak = (k == 0) ? a0F : (k == 1) ? a1F : (k == 2) ? a2F : a3F;
    aVf[u] = ak[d];
  }
  // gather H (f32 emb -> bf16 LDS): rows <100 from emb_table, rows 100..111 zero.
  for (int u = tid; u < LP_ * 16; u += 256) {
    int r = u >> 4, ch = u & 15;                 // ch = which 8-float chunk of the 128-d row
    us8 o = {0, 0, 0, 0, 0, 0, 0, 0};
    if (r < L_) {
      int idx = inp[b * L_ + r];
      const float* src = embF + ((size_t)idx << 7) + ch * 8;
      f4v v0 = *(const f4v*)src;
      f4v v1 = *(const f4v*)(src + 4);
      for (int t = 0; t < 4; ++t) { o[t] = f2b(v0[t]); o[4 + t] = f2b(v1[t]); }
    }
    *(us8*)&Hs[r * SH_ + ch * 8] = o;
  }
  __syncthreads();

  // hoist E-GEMM B-fragments (H rows, n = j). wave w owns n-tiles {w, w+4}
  const int nEB = (w < 3) ? 2 : 1;
  us8 EB[2][4];
  for (int s = 0; s < nEB; ++s) {
    int nt = w + s * 4;
    for (int ks = 0; ks < 4; ++ks)
      EB[s][ks] = *(const us8*)&Hs[(nt * 16 + c) * SH_ + ks * 32 + q * 8];
  }

  for (int mi = 0; mi < 7; ++mi) {
    // adj tile (u8), out-of-range -> 0 (-> NEG_INF later)
    for (int u = tid; u < 2048; u += 256) {
      int r = u >> 7, j = u & 127;
      int ir = mi * 16 + r;
      int val = 0;
      if (j < L_ && ir < L_) val = adjG[((size_t)b * L_ + ir) * L_ + j];
      adjS[u] = (unsigned char)val;
    }
    // U_k = H row * a_k, bf16
    for (int u = tid; u < 8192; u += 256) {
      int k = u >> 11, rem = u & 2047, r = rem >> 7, d = rem & 127;
      float h = b2f(Hs[(mi * 16 + r) * SH_ + d]);
      U4s[k * (16 * SH_) + r * SH_ + d] = f2b(h * aVf[k * 128 + d]);
    }
    __syncthreads();

    // A-fragments: U_k rows (m = i within tile)
    us8 Af[4][4];
    for (int k = 0; k < 4; ++k)
      for (int ks = 0; ks < 4; ++ks)
        Af[k][ks] = *(const us8*)&U4s[k * (16 * SH_) + c * SH_ + ks * 32 + q * 8];

    for (int s = 0; s < nEB; ++s) {
      int nt = w + s * 4;
      f4 acc0 = {0,0,0,0}, acc1 = {0,0,0,0}, acc2 = {0,0,0,0}, acc3 = {0,0,0,0};
      for (int ks = 0; ks < 4; ++ks) {
        bf8 bb = __builtin_bit_cast(bf8, EB[s][ks]);
        acc0 = __builtin_amdgcn_mfma_f32_16x16x32_bf16(__builtin_bit_cast(bf8, Af[0][ks]), bb, acc0, 0, 0, 0);
        acc1 = __builtin_amdgcn_mfma_f32_16x16x32_bf16(__builtin_bit_cast(bf8, Af[1][ks]), bb, acc1, 0, 0, 0);
        acc2 = __builtin_amdgcn_mfma_f32_16x16x32_bf16(__builtin_bit_cast(bf8, Af[2][ks]), bb, acc2, 0, 0, 0);
        acc3 = __builtin_amdgcn_mfma_f32_16x16x32_bf16(__builtin_bit_cast(bf8, Af[3][ks]), bb, acc3, 0, 0, 0);
      }
      // C/D layout: col = lane&15 (=j within tile), row = q*4 + reg (=i within tile)
      int j = nt * 16 + c;
      for (int r = 0; r < 4; ++r) {
        int row = q * 4 + r;
        int t = adjS[row * 128 + j];
        float e = (t == 1) ? acc0[r] : (t == 2) ? acc1[r] : (t == 3) ? acc2[r] : acc3[r];
        e = (e > 0.f) ? e : 0.2f * e;               // leaky_relu(0.2)
        float v = (t >= 1) ? e : -9e15f;            // mask non-edges
        alphaS[row * SA_ + j] = v;
      }
    }
    __syncthreads();

    // softmax: wave w handles rows w*4 .. w*4+3 over 112 cols
    for (int rr = 0; rr < 4; ++rr) {
      int row = w * 4 + rr;
      float v1 = alphaS[row * SA_ + lane];
      float v2 = (lane < LP_ - 64) ? alphaS[row * SA_ + 64 + lane] : -3.0e38f;
      float m = fmaxf(v1, v2);
      for (int off = 32; off > 0; off >>= 1) m = fmaxf(m, __shfl_xor(m, off, 64));
      float x1 = __expf(fmaxf(v1 - m, -80.f));
      float x2 = (lane < LP_ - 64) ? __expf(fmaxf(v2 - m, -80.f)) : 0.f;
      float ssum = x1 + x2;
      for (int off = 32; off > 0; off >>= 1) ssum += __shfl_xor(ssum, off, 64);
      float inv = 1.0f / ssum;
      int ir = mi * 16 + row;
      Ps[ir * SH_ + lane] = f2b(x1 * inv);
      Ps[ir * SH_ + 64 + lane] = (lane < LP_ - 64) ? f2b(x2 * inv) : (ushort_t)0; // zero-pad j 112..127
    }
    __syncthreads();
  }

  // out = P(M=i, K=j) x H(K=j, N=d). B-frag needs H[j][d] with j fast -> 8 scalar
  // LDS reads per frag, built ONCE per wave (amortized over all 7 M-tiles).
  us8 OB[2][4];
  for (int s2 = 0; s2 < 2; ++s2) {
    int nt2 = w * 2 + s2;
    for (int ks = 0; ks < 4; ++ks) {
      us8 vv;
      for (int jj = 0; jj < 8; ++jj) {
        int j = ks * 32 + q * 8 + jj;
        int jc = (j < LP_) ? j : 0;          // clamp: P cols >=112 are zero, avoid garbage
        vv[jj] = Hs[jc * SH_ + nt2 * 16 + c];
      }
      OB[s2][ks] = vv;
    }
  }
  for (int mt = 0; mt < 7; ++mt) {
    us8 Pf[4];
    for (int ks = 0; ks < 4; ++ks)
      Pf[ks] = *(const us8*)&Ps[(mt * 16 + c) * SH_ + ks * 32 + q * 8];
    for (int s2 = 0; s2 < 2; ++s2) {
      int nt2 = w * 2 + s2;
      f4 acc = {0,0,0,0};
      for (int ks = 0; ks < 4; ++ks)
        acc = __builtin_amdgcn_mfma_f32_16x16x32_bf16(__builtin_bit_cast(bf8, Pf[ks]),
                                                      __builtin_bit_cast(bf8, OB[s2][ks]), acc, 0, 0, 0);
      for (int r = 0; r < 4; ++r) {
        int i = mt * 16 + q * 4 + r;
        if (i < L_) outG[((size_t)b * L_ + i) * (size_t)D_ + nt2 * 16 + c] = acc[r];  // f32 output
      }
    }
  }
}

extern "C" void kernel_launch(void* const* d_in, const int* in_sizes, int n_in,
                              void* d_out, int out_size, void* d_ws, size_t ws_size,
                              hipStream_t stream) {
  (void)d_ws; (void)ws_size; (void)out_size;
  // Bind pointers by element count (robust to ordering surprises):
  //   inputs = first 51200, adj = 5120000, emb = 25600000, a0..a3 = the four 128s in order.
  const int* inp = nullptr; const int* adj = nullptr;
  const float* emb = nullptr; const float* aP[4] = {nullptr, nullptr, nullptr, nullptr};
  int na = 0;
  for (int i = 0; i < n_in; ++i) {
    int s = in_sizes[i];
    if (s == 25600000)            emb = (const float*)d_in[i];
    else if (s == 5120000)        adj = (const int*)d_in[i];
    else if (s == 128 && na < 4)  aP[na++] = (const float*)d_in[i];
    else if (s == 51200 && !inp)  inp = (const int*)d_in[i];
  }
  CombineGraph_kernel<<<dim3(B_), dim3(256), 0, stream>>>(
      inp, adj, emb, aP[0], aP[1], aP[2], aP[3], (float*)d_out);
}

// Round 4
// 241.740 us; speedup vs baseline: 2.9277x; 2.9277x over previous
//
#include <hip/hip_runtime.h>
#include <hip/hip_bf16.h>

#define B_  512
#define L_  100
#define LP_ 112      // L padded to 7*16
#define D_  128
#define SH_ 136      // ushort stride of H/P rows (16B-aligned)
#define SA_ 113      // float stride of alpha tile

typedef unsigned short ushort_t;
typedef __attribute__((ext_vector_type(8))) unsigned short us8;
typedef __attribute__((ext_vector_type(8))) __bf16 bf8;
typedef __attribute__((ext_vector_type(4))) float f4;
typedef __attribute__((ext_vector_type(4))) float f4v;
typedef __attribute__((ext_vector_type(4))) unsigned int ui4;

__device__ __forceinline__ float b2f(ushort_t u) {
  union { unsigned i; float f; } v; v.i = ((unsigned)u) << 16; return v.f;
}
__device__ __forceinline__ ushort_t f2b(float f) {
  unsigned u = __float_as_uint(f);
  u += 0x7fffu + ((u >> 16) & 1u);   // RNE
  return (ushort_t)(u >> 16);
}
// pack 8 f32 -> 8 bf16 via v_cvt_pk_bf16_f32 (RNE)
__device__ __forceinline__ us8 pack8(const float* x) {
  union { __hip_bfloat162 h; unsigned u; } cv;
  ui4 pk;
#pragma unroll
  for (int t = 0; t < 4; ++t) {
    cv.h = __float22bfloat162_rn(make_float2(x[2 * t], x[2 * t + 1]));
    pk[t] = cv.u;
  }
  return __builtin_bit_cast(us8, pk);
}

// grid = (512 batches, 7 M-tiles); block = 256 threads (4 waves).
// Per block: gather all 112 H rows (bf16, LDS), stage 16x128 adj tile,
// E = (H_tile . a_k) x H^T via MFMA with a_k folded into register A-frags,
// masked-select + leaky + softmax (16 rows), P-tile x H via MFMA, store f32.
__global__ __launch_bounds__(256, 3)
void CombineGraph_kernel(const int* __restrict__ inp, const int* __restrict__ adjG,
                         const float* __restrict__ embF,
                         const float* __restrict__ a0F, const float* __restrict__ a1F,
                         const float* __restrict__ a2F, const float* __restrict__ a3F,
                         float* __restrict__ outG) {
  __shared__ __align__(16) ushort_t Hs[LP_ * SH_];   // 30464 B  all h rows (bf16)
  __shared__ __align__(16) ushort_t Pt[16 * SH_];    //  4352 B  softmaxed P tile, cols>=112 zero
  __shared__ float    alphaS[16 * SA_];              //  7232 B  masked logits f32
  __shared__ unsigned char adjS[16 * 128];           //  2048 B
  __shared__ float    aVf[4 * 128];                  //  2048 B
  // total ~46.1 KB -> 3 blocks/CU by LDS

  const int b = blockIdx.x;
  const int mi = blockIdx.y;
  const int tid = threadIdx.x;
  const int w = tid >> 6, lane = tid & 63;
  const int c = lane & 15, q = lane >> 4;

  // ---- stage a_k (f32), H (f32 emb -> bf16), adj tile ----
  for (int u = tid; u < 512; u += 256) {
    int k = u >> 7, d = u & 127;
    const float* ak = (k == 0) ? a0F : (k == 1) ? a1F : (k == 2) ? a2F : a3F;
    aVf[u] = ak[d];
  }
  for (int u = tid; u < LP_ * 16; u += 256) {        // 7 iters: 112 rows x 16 chunks of 8 floats
    int r = u >> 4, ch = u & 15;
    us8 o = {0, 0, 0, 0, 0, 0, 0, 0};
    if (r < L_) {
      int idx = inp[b * L_ + r];
      const float* src = embF + ((size_t)idx << 7) + ch * 8;
      float x[8];
      f4v v0 = *(const f4v*)src;
      f4v v1 = *(const f4v*)(src + 4);
#pragma unroll
      for (int t = 0; t < 4; ++t) { x[t] = v0[t]; x[4 + t] = v1[t]; }
      o = pack8(x);
    }
    *(us8*)&Hs[r * SH_ + ch * 8] = o;
  }
  for (int u = tid; u < 2048; u += 256) {            // 16 x 128 adj tile
    int r = u >> 7, j = u & 127;
    int ir = mi * 16 + r;
    int val = 0;
    if (j < L_ && ir < L_) val = adjG[((size_t)b * L_ + ir) * L_ + j];
    adjS[u] = (unsigned char)val;
  }
  __syncthreads();

  // ---- build A-fragments with a_k folded in (registers only) ----
  // lane holds A row m = c (global row mi*16+c), k-slice ks: d = ks*32 + q*8 + jj
  float hf[4][8];
#pragma unroll
  for (int ks = 0; ks < 4; ++ks) {
    us8 hr = *(const us8*)&Hs[(mi * 16 + c) * SH_ + ks * 32 + q * 8];
#pragma unroll
    for (int jj = 0; jj < 8; ++jj) hf[ks][jj] = b2f(hr[jj]);
  }
  us8 Af[4][4];
#pragma unroll
  for (int k = 0; k < 4; ++k)
#pragma unroll
    for (int ks = 0; ks < 4; ++ks) {
      const float* ap = &aVf[k * 128 + ks * 32 + q * 8];
      f4v a0v = *(const f4v*)ap;
      f4v a1v = *(const f4v*)(ap + 4);
      float p[8];
#pragma unroll
      for (int t = 0; t < 4; ++t) { p[t] = hf[ks][t] * a0v[t]; p[4 + t] = hf[ks][4 + t] * a1v[t]; }
      Af[k][ks] = pack8(p);
    }

  // ---- E GEMM: 7 j-tiles over 4 waves (waves 0-2 take 2, wave 3 takes 1) ----
  const int nEB = (w < 3) ? 2 : 1;
  f4 acc[2][4];
#pragma unroll
  for (int s = 0; s < 2; ++s)
#pragma unroll
    for (int k = 0; k < 4; ++k) acc[s][k] = (f4){0.f, 0.f, 0.f, 0.f};

  for (int s = 0; s < nEB; ++s) {
    int nt = w + s * 4;
#pragma unroll
    for (int ks = 0; ks < 4; ++ks) {
      bf8 bb = __builtin_bit_cast(bf8, *(const us8*)&Hs[(nt * 16 + c) * SH_ + ks * 32 + q * 8]);
      acc[s][0] = __builtin_amdgcn_mfma_f32_16x16x32_bf16(__builtin_bit_cast(bf8, Af[0][ks]), bb, acc[s][0], 0, 0, 0);
      acc[s][1] = __builtin_amdgcn_mfma_f32_16x16x32_bf16(__builtin_bit_cast(bf8, Af[1][ks]), bb, acc[s][1], 0, 0, 0);
      acc[s][2] = __builtin_amdgcn_mfma_f32_16x16x32_bf16(__builtin_bit_cast(bf8, Af[2][ks]), bb, acc[s][2], 0, 0, 0);
      acc[s][3] = __builtin_amdgcn_mfma_f32_16x16x32_bf16(__builtin_bit_cast(bf8, Af[3][ks]), bb, acc[s][3], 0, 0, 0);
    }
    // C/D: col = lane&15 (=j in tile), row = q*4 + r (=i in tile)
    int j = nt * 16 + c;
#pragma unroll
    for (int r = 0; r < 4; ++r) {
      int row = q * 4 + r;
      int t = adjS[row * 128 + j];
      float e = (t == 1) ? acc[s][0][r] : (t == 2) ? acc[s][1][r] : (t == 3) ? acc[s][2][r] : acc[s][3][r];
      e = (e > 0.f) ? e : 0.2f * e;               // leaky_relu(0.2)
      alphaS[row * SA_ + j] = (t >= 1) ? e : -9e15f;
    }
  }
  __syncthreads();

  // ---- softmax: wave w -> rows w*4..w*4+3 over 112 cols; write P tile (bf16) ----
#pragma unroll
  for (int rr = 0; rr < 4; ++rr) {
    int row = w * 4 + rr;
    float v1 = alphaS[row * SA_ + lane];
    float v2 = (lane < LP_ - 64) ? alphaS[row * SA_ + 64 + lane] : -3.0e38f;
    float m = fmaxf(v1, v2);
    for (int off = 32; off > 0; off >>= 1) m = fmaxf(m, __shfl_xor(m, off, 64));
    float x1 = __expf(fmaxf(v1 - m, -80.f));
    float x2 = (lane < LP_ - 64) ? __expf(fmaxf(v2 - m, -80.f)) : 0.f;
    float ssum = x1 + x2;
    for (int off = 32; off > 0; off >>= 1) ssum += __shfl_xor(ssum, off, 64);
    float inv = 1.0f / ssum;
    Pt[row * SH_ + lane] = f2b(x1 * inv);
    Pt[row * SH_ + 64 + lane] = (lane < LP_ - 64) ? f2b(x2 * inv) : (ushort_t)0;  // zero K-pad 112..127
  }
  __syncthreads();

  // ---- out = P(16 x 112pad128) x H(112 x 128): 8 n-tiles over 4 waves ----
  us8 Pf[4];
#pragma unroll
  for (int ks = 0; ks < 4; ++ks)
    Pf[ks] = *(const us8*)&Pt[c * SH_ + ks * 32 + q * 8];
#pragma unroll
  for (int s2 = 0; s2 < 2; ++s2) {
    int nt2 = w * 2 + s2;
    us8 OB[4];
#pragma unroll
    for (int ks = 0; ks < 4; ++ks) {
      us8 vv;
#pragma unroll
      for (int jj = 0; jj < 8; ++jj) {
        int j = ks * 32 + q * 8 + jj;
        int jc = (j < LP_) ? j : 0;          // P is zero there; clamp keeps values finite
        vv[jj] = Hs[jc * SH_ + nt2 * 16 + c];
      }
      OB[ks] = vv;
    }
    f4 oacc = {0.f, 0.f, 0.f, 0.f};
#pragma unroll
    for (int ks = 0; ks < 4; ++ks)
      oacc = __builtin_amdgcn_mfma_f32_16x16x32_bf16(__builtin_bit_cast(bf8, Pf[ks]),
                                                     __builtin_bit_cast(bf8, OB[ks]), oacc, 0, 0, 0);
#pragma unroll
    for (int r = 0; r < 4; ++r) {
      int i = mi * 16 + q * 4 + r;
      if (i < L_) outG[((size_t)b * L_ + i) * (size_t)D_ + nt2 * 16 + c] = oacc[r];
    }
  }
}

extern "C" void kernel_launch(void* const* d_in, const int* in_sizes, int n_in,
                              void* d_out, int out_size, void* d_ws, size_t ws_size,
                              hipStream_t stream) {
  (void)d_ws; (void)ws_size; (void)out_size;
  const int* inp = nullptr; const int* adj = nullptr;
  const float* emb = nullptr; const float* aP[4] = {nullptr, nullptr, nullptr, nullptr};
  int na = 0;
  for (int i = 0; i < n_in; ++i) {
    int s = in_sizes[i];
    if (s == 25600000)            emb = (const float*)d_in[i];
    else if (s == 5120000)        adj = (const int*)d_in[i];
    else if (s == 128 && na < 4)  aP[na++] = (const float*)d_in[i];
    else if (s == 51200 && !inp)  inp = (const int*)d_in[i];
  }
  CombineGraph_kernel<<<dim3(B_, 7), dim3(256), 0, stream>>>(
      inp, adj, emb, aP[0], aP[1], aP[2], aP[3], (float*)d_out);
}